// Round 11
// baseline (166.878 us; speedup 1.0000x reference)
//
#include <hip/hip_runtime.h>
#include <cstdint>
#include <cstddef>

#define DIM 128
#define BM 128
#define NB1 128          // blocks for bucket hist/scatter
#define RBITS 14         // degree-histogram range bits
#define RSIZE (1 << RBITS)
#define NB2 32           // chunks per degree range
#define NWC 4            // W-convert task-blocks

typedef __attribute__((ext_vector_type(8))) short bf16x8;
typedef __attribute__((ext_vector_type(16))) float f32x16;

__device__ inline unsigned short f2b(float x) {  // fp32 -> bf16 RNE
    unsigned int u = __float_as_uint(x);
    unsigned int r = (u + 0x7fffu + ((u >> 16) & 1u)) >> 16;
    return (unsigned short)r;
}
__device__ inline float blo(unsigned int u) { return __uint_as_float(u << 16); }
__device__ inline float bhi(unsigned int u) { return __uint_as_float(u & 0xffff0000u); }

struct GArgs {
    const float* x; const int* row; const int* col;
    const float* Wt; const float* bt; const float* Wg; const float* bg;
    unsigned short* wbuf; unsigned short* h1b; unsigned short* hbuf;
    float* dinv; float* a; float* praw; float* out;
    int* off; int* csr; unsigned int* tmp; int* counts; int* bstart; int* tot;
    int* gcounts;
    int n, E, nbuk, bshift, ndeg, nscan, ndinv, gt, ga;
};

// ---- transform body: bf16 MFMA GEMM ---------------------------------------
// wfromf32: stage W from fp32 Wt (convert+swizzle); else linear copy of wbuf.
// fullepi:  aout = tanh(p+bg)*dinv ; else aout = p (raw gate partial).
__device__ void transform_body(bool bf16in, bool wfromf32, const void* hin_v,
    const float* WtL, const unsigned short* wbufL,
    const float* btL, const float* WgL, float bgL,
    const float* dinv, unsigned short* h1b, float* aout, bool fullepi,
    int n, int tb, unsigned short* h_s, unsigned short* w_s, float* p_s)
{
    const int tid = threadIdx.x;
    const int node0 = tb * BM;
    const int lane = tid & 63;
    const int wv = tid >> 6;

    if (wfromf32) {
#pragma unroll
        for (int it = 0; it < 16; ++it) {
            int g = it * 256 + tid;
            int r = g >> 5;
            int c4 = g & 31;
            int chunk = (c4 >> 1) ^ (r & 15);
            int base = r * DIM + chunk * 8 + (c4 & 1) * 4;
            float4 wvv = *(const float4*)(WtL + (size_t)r * DIM + c4 * 4);
            w_s[base + 0] = f2b(wvv.x); w_s[base + 1] = f2b(wvv.y);
            w_s[base + 2] = f2b(wvv.z); w_s[base + 3] = f2b(wvv.w);
        }
    } else {
#pragma unroll
        for (int it = 0; it < 8; ++it) {
            int g = it * 256 + tid;
            ((int4*)w_s)[g] = ((const int4*)wbufL)[g];
        }
    }
    if (bf16in) {
        const int4* hin = (const int4*)hin_v;   // pre-swizzled bf16 rows
#pragma unroll
        for (int it = 0; it < 8; ++it) {
            int g = it * 256 + tid;
            int r = g >> 4;
            int src = node0 + r;
            if (src >= n) src = n - 1;
            ((int4*)h_s)[g] = hin[(size_t)src * 16 + (g & 15)];
        }
    } else {
        const float* hin = (const float*)hin_v;
#pragma unroll
        for (int it = 0; it < 16; ++it) {
            int g = it * 256 + tid;
            int r = g >> 5;
            int c4 = g & 31;
            int src = node0 + r;
            if (src >= n) src = n - 1;
            float4 hv = *(const float4*)(hin + (size_t)src * DIM + c4 * 4);
            int chunk = (c4 >> 1) ^ (r & 15);
            int base = r * DIM + chunk * 8 + (c4 & 1) * 4;
            h_s[base + 0] = f2b(hv.x); h_s[base + 1] = f2b(hv.y);
            h_s[base + 2] = f2b(hv.z); h_s[base + 3] = f2b(hv.w);
        }
    }
    __syncthreads();

    f32x16 acc[4] = {};
    const int l31 = lane & 31;
    const int asel = lane >> 5;
    const int swz = l31 & 15;
    const unsigned short* ha = h_s + (wv * 32 + l31) * DIM;
#pragma unroll
    for (int ks = 0; ks < 8; ++ks) {
        int ch = ((ks * 2 + asel) ^ swz) * 8;
        bf16x8 av = *(const bf16x8*)(ha + ch);
#pragma unroll
        for (int cf = 0; cf < 4; ++cf) {
            bf16x8 bv = *(const bf16x8*)(w_s + (cf * 32 + l31) * DIM + ch);
            acc[cf] = __builtin_amdgcn_mfma_f32_32x32x16_bf16(av, bv, acc[cf], 0, 0, 0);
        }
    }
    __syncthreads();

    float btc[4], wgc[4];
#pragma unroll
    for (int cf = 0; cf < 4; ++cf) {
        btc[cf] = btL[cf * 32 + l31];
        wgc[cf] = WgL[cf * 32 + l31];
    }
    float p[16];
#pragma unroll
    for (int q = 0; q < 16; ++q) p[q] = 0.0f;
#pragma unroll
    for (int cf = 0; cf < 4; ++cf) {
#pragma unroll
        for (int q = 0; q < 16; ++q) {
            float v = acc[cf][q] + btc[cf];
            p[q] = fmaf(v, wgc[cf], p[q]);
            int rr = (q & 3) + 8 * (q >> 2) + 4 * asel;
            h_s[(wv * 32 + rr) * DIM + cf * 32 + l31] = f2b(v);
        }
    }
#pragma unroll
    for (int m = 1; m < 32; m <<= 1) {
#pragma unroll
        for (int q = 0; q < 16; ++q) p[q] += __shfl_xor(p[q], m, 64);
    }
    if (l31 == 0) {
#pragma unroll
        for (int q = 0; q < 16; ++q) {
            int rr = (q & 3) + 8 * (q >> 2) + 4 * asel;
            p_s[wv * 32 + rr] = p[q];
        }
    }
    __syncthreads();

#pragma unroll
    for (int it = 0; it < 8; ++it) {
        int g = it * 256 + tid;
        int r = g >> 4;
        int c = g & 15;
        int4 v = *(const int4*)(h_s + r * DIM + c * 8);
        int dst = node0 + r;
        if (dst < n) *(int4*)(h1b + (size_t)dst * DIM + c * 8) = v;
    }

    if (tid < BM) {
        int node = node0 + tid;
        if (node < n) {
            if (fullepi) aout[node] = tanhf(p_s[tid] + bgL) * dinv[node];
            else         aout[node] = p_s[tid];
        }
    }
}

// ---- K1: deg hist + col hist + W convert + T0-core (all independent) -------
__global__ __launch_bounds__(256) void mega1_kernel(GArgs A) {
    __shared__ __align__(16) unsigned char smem[66048];
    int b = blockIdx.x;
    if (b < A.ndeg) {
        int* hs = (int*)smem;   // 64 KB
        int r = b / NB2, bi = b % NB2;
        for (int i = threadIdx.x; i < RSIZE; i += 256) hs[i] = 0;
        __syncthreads();
        int chunk = (A.E + NB2 - 1) / NB2;
        int e0 = bi * chunk, e1 = min(A.E, e0 + chunk);
        for (int e = e0 + threadIdx.x; e < e1; e += 256) {
            int rv = A.row[e];
            if ((rv >> RBITS) == r) atomicAdd(&hs[rv & (RSIZE - 1)], 1);
        }
        __syncthreads();
        int* outp = A.gcounts + (size_t)b * RSIZE;
        for (int i = threadIdx.x; i < RSIZE; i += 256) outp[i] = hs[i];
    } else if (b < A.ndeg + NB1) {
        int* hs = (int*)smem;
        int hb = b - A.ndeg;
        for (int i = threadIdx.x; i < A.nbuk; i += 256) hs[i] = 0;
        __syncthreads();
        int chunk = (A.E + NB1 - 1) / NB1;
        int e0 = hb * chunk, e1 = min(A.E, e0 + chunk);
        for (int e = e0 + threadIdx.x; e < e1; e += 256)
            atomicAdd(&hs[A.col[e] >> A.bshift], 1);
        __syncthreads();
        int* outp = A.counts + (size_t)hb * A.nbuk;
        for (int i = threadIdx.x; i < A.nbuk; i += 256) outp[i] = hs[i];
    } else if (b < A.ndeg + NB1 + NWC) {
        int b2 = b - A.ndeg - NB1;   // 0..3  (wbuf for layer-1 transform)
#pragma unroll
        for (int k = 0; k < 4; ++k) {
            int idx = b2 * 1024 + k * 256 + threadIdx.x;   // 0..4095
            int L = idx >> 11;
            int rem = idx & 2047;
            int r = rem >> 4;
            int cc = rem & 15;
            const float* src = A.Wt + (size_t)L * DIM * DIM + r * DIM + cc * 8;
            float4 v0 = *(const float4*)(src);
            float4 v1 = *(const float4*)(src + 4);
            unsigned short o[8];
            o[0] = f2b(v0.x); o[1] = f2b(v0.y); o[2] = f2b(v0.z); o[3] = f2b(v0.w);
            o[4] = f2b(v1.x); o[5] = f2b(v1.y); o[6] = f2b(v1.z); o[7] = f2b(v1.w);
            unsigned short* dst = A.wbuf + (size_t)L * DIM * DIM + r * DIM + (cc ^ (r & 15)) * 8;
            *(int4*)dst = *(const int4*)o;
        }
    } else {
        int tb = b - (A.ndeg + NB1 + NWC);
        unsigned short* h_s = (unsigned short*)smem;
        unsigned short* w_s = h_s + BM * DIM;
        float* p_s = (float*)(w_s + DIM * DIM);
        transform_body(false, true, A.x, A.Wt, nullptr, A.bt, A.Wg, 0.0f,
                       nullptr, A.h1b, A.praw, false, A.n, tb, h_s, w_s, p_s);
    }
}

// ---- K2: per-bucket column scan of NB1 block counts + dinv -----------------
__global__ __launch_bounds__(256) void scan_dinv_kernel(GArgs A) {
    int b = blockIdx.x;
    if (b < A.nscan) {
        int w = threadIdx.x >> 6;
        int lane = threadIdx.x & 63;
        int t = b * 4 + w;
        if (t >= A.nbuk) return;
        int c0 = A.counts[(size_t)(lane * 2) * A.nbuk + t];
        int c1 = A.counts[(size_t)(lane * 2 + 1) * A.nbuk + t];
        int s = c0 + c1;
        int x = s;
#pragma unroll
        for (int d = 1; d < 64; d <<= 1) {
            int y = __shfl_up(x, (unsigned)d, 64);
            if (lane >= d) x += y;
        }
        int excl = x - s;
        A.counts[(size_t)(lane * 2) * A.nbuk + t] = excl;
        A.counts[(size_t)(lane * 2 + 1) * A.nbuk + t] = excl + c0;
        if (lane == 63) A.tot[t] = x;
    } else {
        int i = (b - A.nscan) * 256 + threadIdx.x;
        if (i >= A.n) return;
        int r = i >> RBITS, bl = i & (RSIZE - 1);
        int s = 0;
        for (int bi = 0; bi < NB2; ++bi)
            s += A.gcounts[(size_t)(r * NB2 + bi) * RSIZE + bl];
        A.dinv[i] = rsqrtf((float)max(s, 1));
    }
}

// ---- K3: scatter (with inline bstart prefix) + afin blocks -----------------
__global__ __launch_bounds__(256) void scatter_kernel(GArgs A) {
    int b = blockIdx.x;
    int t = threadIdx.x;
    if (b >= NB1) {
        // afin: a[i] = tanh(praw[i] + bg0) * dinv[i]
        int i = (b - NB1) * 256 + t;
        if (i < A.n) A.a[i] = tanhf(A.praw[i] + A.bg[0]) * A.dinv[i];
        return;
    }
    __shared__ int scanbuf[256];
    __shared__ int bst[1024];
    __shared__ int cur[1024];
    int v[4];
    int s = 0;
#pragma unroll
    for (int k = 0; k < 4; ++k) {
        int idx = t * 4 + k;
        v[k] = (idx < A.nbuk) ? A.tot[idx] : 0;
        s += v[k];
    }
    scanbuf[t] = s;
    __syncthreads();
    for (int d = 1; d < 256; d <<= 1) {
        int y = (t >= d) ? scanbuf[t - d] : 0;
        __syncthreads();
        scanbuf[t] += y;
        __syncthreads();
    }
    int run = scanbuf[t] - s;
#pragma unroll
    for (int k = 0; k < 4; ++k) {
        int idx = t * 4 + k;
        if (idx < A.nbuk) bst[idx] = run;
        run += v[k];
    }
    __syncthreads();
    const int* mybase = A.counts + (size_t)b * A.nbuk;
    for (int i = t; i < A.nbuk; i += 256) cur[i] = bst[i] + mybase[i];
    if (b == 0) {
        for (int i = t; i < A.nbuk; i += 256) A.bstart[i] = bst[i];
        if (t == 0) A.bstart[A.nbuk] = A.E;
    }
    __syncthreads();
    int chunk = (A.E + NB1 - 1) / NB1;
    int e0 = b * chunk, e1 = min(A.E, e0 + chunk);
    int rsh = 32 - A.bshift;
    unsigned int smask = (1u << A.bshift) - 1u;
    for (int e = e0 + t; e < e1; e += 256) {
        int c = A.col[e];
        int pos = atomicAdd(&cur[c >> A.bshift], 1);
        A.tmp[pos] = (((unsigned int)c & smask) << rsh) | (unsigned int)A.row[e];
    }
}

// ---- K4: group each bucket by exact col; emit off[] and csr[] --------------
__global__ __launch_bounds__(256) void bucket_group_kernel(GArgs A) {
    __shared__ int subh[4096];
    const int b = blockIdx.x;
    const int tid = threadIdx.x;
    const int subb = 1 << A.bshift;
    const int rsh = 32 - A.bshift;
    const unsigned int rmask = (1u << rsh) - 1u;
    int beg = A.bstart[b], end = A.bstart[b + 1];

    for (int i = tid; i < subb; i += 256) subh[i] = 0;
    __syncthreads();
    for (int i = beg + tid; i < end; i += 256)
        atomicAdd(&subh[A.tmp[i] >> rsh], 1);
    __syncthreads();
    if (subb <= 64) {
        if (tid < 64) {
            int v = (tid < subb) ? subh[tid] : 0;
            int x = v;
            for (int d = 1; d < 64; d <<= 1) {
                int y = __shfl_up(x, (unsigned)d, 64);
                if (tid >= d) x += y;
            }
            if (tid < subb) subh[tid] = x - v;
        }
    } else {
        if (tid == 0) {
            int run = 0;
            for (int i = 0; i < subb; ++i) { int c = subh[i]; subh[i] = run; run += c; }
        }
    }
    __syncthreads();
    int c0 = b << A.bshift;
    for (int i = tid; i < subb; i += 256) {
        int c = c0 + i;
        if (c < A.n) A.off[c] = beg + subh[i];
    }
    if (b == (int)gridDim.x - 1 && tid == 0) A.off[A.n] = A.E;
    __syncthreads();
    for (int i = beg + tid; i < end; i += 256) {
        unsigned int v = A.tmp[i];
        int rank = atomicAdd(&subh[v >> rsh], 1);
        A.csr[beg + rank] = (int)(v & rmask);
    }
}

// ---- K6: layer-1 transform (full epilogue, W from wbuf, bf16 input) --------
__global__ __launch_bounds__(256) void t1_kernel(GArgs A) {
    __shared__ __align__(16) unsigned short h_s[BM * DIM];
    __shared__ __align__(16) unsigned short w_s[DIM * DIM];
    __shared__ float p_s[BM];
    transform_body(true, false, A.hbuf, nullptr, A.wbuf + DIM * DIM,
                   A.bt + DIM, A.Wg + DIM, A.bg[1], A.dinv, A.h1b, A.a, true,
                   A.n, blockIdx.x, h_s, w_s, p_s);
}

// ---- K5/K7: aggregation out[c] = relu(dinv[c]*sum(a[r]*h1[r]) + h1[c]) -----
template <bool BF16OUT>
__global__ __launch_bounds__(256) void agg_kernel(GArgs A, void* out_v) {
    int node = blockIdx.x * 4 + (threadIdx.x >> 6);
    if (node >= A.n) return;
    int lane = threadIdx.x & 63;
    int beg = A.off[node], end = A.off[node + 1];
    const unsigned int* hb = (const unsigned int*)A.h1b;
    float s0x = 0.f, s0y = 0.f, s1x = 0.f, s1y = 0.f;
    float s2x = 0.f, s2y = 0.f, s3x = 0.f, s3y = 0.f;
    int s = beg;
    for (; s + 4 <= end; s += 4) {
        int r0 = A.csr[s], r1 = A.csr[s + 1], r2 = A.csr[s + 2], r3 = A.csr[s + 3];
        float a0 = A.a[r0], a1 = A.a[r1], a2 = A.a[r2], a3 = A.a[r3];
        unsigned int u0 = hb[(size_t)r0 * 64 + lane];
        unsigned int u1 = hb[(size_t)r1 * 64 + lane];
        unsigned int u2 = hb[(size_t)r2 * 64 + lane];
        unsigned int u3 = hb[(size_t)r3 * 64 + lane];
        s0x = fmaf(a0, blo(u0), s0x); s0y = fmaf(a0, bhi(u0), s0y);
        s1x = fmaf(a1, blo(u1), s1x); s1y = fmaf(a1, bhi(u1), s1y);
        s2x = fmaf(a2, blo(u2), s2x); s2y = fmaf(a2, bhi(u2), s2y);
        s3x = fmaf(a3, blo(u3), s3x); s3y = fmaf(a3, bhi(u3), s3y);
    }
    for (; s < end; ++s) {
        int r0 = A.csr[s];
        float a0 = A.a[r0];
        unsigned int u0 = hb[(size_t)r0 * 64 + lane];
        s0x = fmaf(a0, blo(u0), s0x); s0y = fmaf(a0, bhi(u0), s0y);
    }
    float dv = A.dinv[node];
    unsigned int ur = hb[(size_t)node * 64 + lane];
    float ox = fmaxf(fmaf(dv, s0x + s1x + s2x + s3x, blo(ur)), 0.0f);
    float oy = fmaxf(fmaf(dv, s0y + s1y + s2y + s3y, bhi(ur)), 0.0f);
    if constexpr (BF16OUT) {
        unsigned int pk = (unsigned int)f2b(ox) | ((unsigned int)f2b(oy) << 16);
        int pos = (((lane >> 2) ^ (node & 15)) << 2) + (lane & 3);
        __builtin_nontemporal_store(pk, (unsigned int*)out_v + (size_t)node * 64 + pos);
    } else {
        float* fp = (float*)out_v + ((size_t)node * 64 + lane) * 2;
        __builtin_nontemporal_store(ox, fp);
        __builtin_nontemporal_store(oy, fp + 1);
    }
}

extern "C" void kernel_launch(void* const* d_in, const int* in_sizes, int n_in,
                              void* d_out, int out_size, void* d_ws, size_t ws_size,
                              hipStream_t stream) {
    const float* x    = (const float*)d_in[0];
    const int*   edge = (const int*)d_in[1];
    const float* Wt   = (const float*)d_in[2];
    const float* bt   = (const float*)d_in[3];
    const float* Wg   = (const float*)d_in[4];
    const float* bg   = (const float*)d_in[5];

    const int n = in_sizes[0] / DIM;      // 50000
    const int E = in_sizes[1] / 2;        // 600000

    int bshift = 6;
    while (((n + (1 << bshift) - 1) >> bshift) > 1024) ++bshift;
    const int nbuk = (n + (1 << bshift) - 1) >> bshift;
    const int nr = (n + RSIZE - 1) >> RBITS;
    const int ndeg = nr * NB2;

    // ---- byte-carved workspace ----
    char* base = (char*)d_ws;
    size_t o = 0;
    auto carve = [&](size_t bytes) -> void* {
        void* p = base + o;
        o += (bytes + 255) & ~(size_t)255;
        return p;
    };
    GArgs A;
    A.x = x; A.row = edge; A.col = edge + E;
    A.Wt = Wt; A.bt = bt; A.Wg = Wg; A.bg = bg;
    A.out = (float*)d_out;
    A.h1b   = (unsigned short*)carve((size_t)n * DIM * 2);
    A.hbuf  = (unsigned short*)carve((size_t)n * DIM * 2);
    A.wbuf  = (unsigned short*)carve((size_t)2 * DIM * DIM * 2);
    A.dinv  = (float*)carve((size_t)n * 4);
    A.a     = (float*)carve((size_t)n * 4);
    A.praw  = (float*)carve((size_t)n * 4);
    A.off   = (int*)carve((size_t)(n + 1) * 4);
    A.csr   = (int*)carve((size_t)E * 4);
    A.tmp   = (unsigned int*)carve((size_t)E * 4);
    A.counts = (int*)carve((size_t)NB1 * nbuk * 4);
    A.bstart = (int*)carve((size_t)(nbuk + 1) * 4);
    A.tot    = (int*)carve((size_t)nbuk * 4);
    A.gcounts = (int*)carve((size_t)ndeg * RSIZE * 4);
    A.n = n; A.E = E; A.nbuk = nbuk; A.bshift = bshift; A.ndeg = ndeg;
    A.nscan = (nbuk + 3) / 4;
    A.ndinv = (n + 255) / 256;
    A.gt = (n + BM - 1) / BM;
    A.ga = (n + 3) / 4;

    // ---- 7 launches ----
    mega1_kernel<<<ndeg + NB1 + NWC + A.gt, 256, 0, stream>>>(A);
    scan_dinv_kernel<<<A.nscan + A.ndinv, 256, 0, stream>>>(A);
    scatter_kernel<<<NB1 + A.ndinv, 256, 0, stream>>>(A);
    bucket_group_kernel<<<nbuk, 256, 0, stream>>>(A);
    agg_kernel<true><<<A.ga, 256, 0, stream>>>(A, A.hbuf);
    t1_kernel<<<A.gt, 256, 0, stream>>>(A);
    agg_kernel<false><<<A.ga, 256, 0, stream>>>(A, A.out);
}

// Round 12
// 148.943 us; speedup vs baseline: 1.1204x; 1.1204x over previous
//
#include <hip/hip_runtime.h>
#include <cstdint>
#include <cstddef>

#define DIM 128
#define BM 128
#define NB1 128          // blocks for bucket hist/scatter
#define RBITS 15         // degree-histogram range bits (packed 16-bit counters)
#define RSIZE (1 << RBITS)
#define HWORDS (RSIZE / 2)
#define NB2 32           // chunks per degree range
#define NWC 4            // W-convert blocks fused into hists

typedef __attribute__((ext_vector_type(8))) short bf16x8;
typedef __attribute__((ext_vector_type(16))) float f32x16;

__device__ inline unsigned short f2b(float x) {  // fp32 -> bf16 RNE
    unsigned int u = __float_as_uint(x);
    unsigned int r = (u + 0x7fffu + ((u >> 16) & 1u)) >> 16;
    return (unsigned short)r;
}
__device__ inline float blo(unsigned int u) { return __uint_as_float(u << 16); }
__device__ inline float bhi(unsigned int u) { return __uint_as_float(u & 0xffff0000u); }

// ---- K_A: fused histograms + W pre-convert ---------------------------------
// blocks [0, ndeg): out-degree range histograms, two 16-bit counters per word
//   (overflow-free: per-chunk per-node count <= E/NB2 = 18750 < 2^16)
// blocks [ndeg, ndeg+NB1): coarse col>>bshift histogram per E/NB1 chunk
// blocks [ndeg+NB1, +NWC): Wt fp32 -> swizzled bf16 wbuf (both layers)
__global__ __launch_bounds__(256) void hists_kernel(
    const int* __restrict__ row, const int* __restrict__ col,
    const float* __restrict__ Wt, unsigned short* __restrict__ wbuf,
    unsigned int* __restrict__ gcounts, int* __restrict__ counts,
    int E, int ndeg, int nbuk, int bshift)
{
    __shared__ unsigned int hs[HWORDS];   // 64 KB
    int b = blockIdx.x;
    if (b < ndeg) {
        int r = b / NB2, bi = b % NB2;
        for (int i = threadIdx.x; i < HWORDS; i += 256) hs[i] = 0;
        __syncthreads();
        int chunk = (E + NB2 - 1) / NB2;
        int e0 = bi * chunk, e1 = min(E, e0 + chunk);
        for (int e = e0 + threadIdx.x; e < e1; e += 256) {
            int rv = row[e];
            if ((rv >> RBITS) == r)
                atomicAdd(&hs[(rv & (RSIZE - 1)) >> 1], 1u << ((rv & 1) << 4));
        }
        __syncthreads();
        unsigned int* outp = gcounts + (size_t)b * HWORDS;
        for (int i = threadIdx.x; i < HWORDS; i += 256) outp[i] = hs[i];
    } else if (b < ndeg + NB1) {
        int hb = b - ndeg;
        for (int i = threadIdx.x; i < nbuk; i += 256) hs[i] = 0;
        __syncthreads();
        int chunk = (E + NB1 - 1) / NB1;
        int e0 = hb * chunk, e1 = min(E, e0 + chunk);
        for (int e = e0 + threadIdx.x; e < e1; e += 256)
            atomicAdd(&hs[col[e] >> bshift], 1u);
        __syncthreads();
        int* outp = counts + (size_t)hb * nbuk;
        for (int i = threadIdx.x; i < nbuk; i += 256) outp[i] = (int)hs[i];
    } else {
        // W convert: 4096 16B chunks total (2 layers x 128 rows x 16 chunks)
        int b2 = b - ndeg - NB1;
#pragma unroll
        for (int k = 0; k < 4; ++k) {
            int idx = b2 * 1024 + k * 256 + threadIdx.x;   // 0..4095
            int L = idx >> 11;
            int rem = idx & 2047;
            int r = rem >> 4;
            int cc = rem & 15;
            const float* src = Wt + (size_t)L * DIM * DIM + r * DIM + cc * 8;
            float4 v0 = *(const float4*)(src);
            float4 v1 = *(const float4*)(src + 4);
            unsigned short o[8];
            o[0] = f2b(v0.x); o[1] = f2b(v0.y); o[2] = f2b(v0.z); o[3] = f2b(v0.w);
            o[4] = f2b(v1.x); o[5] = f2b(v1.y); o[6] = f2b(v1.z); o[7] = f2b(v1.w);
            unsigned short* dst = wbuf + (size_t)L * DIM * DIM + r * DIM + (cc ^ (r & 15)) * 8;
            *(int4*)dst = *(const int4*)o;
        }
    }
}

// ---- K_B: fused {per-bucket column scan of NB1 block counts} + {dinv} ------
__global__ __launch_bounds__(256) void scan_dinv_kernel(
    int* __restrict__ counts, int* __restrict__ tot,
    const unsigned int* __restrict__ gcounts, float* __restrict__ dinv,
    int nbuk, int n, int nscan)
{
    int b = blockIdx.x;
    if (b < nscan) {
        int w = threadIdx.x >> 6;
        int lane = threadIdx.x & 63;
        int t = b * 4 + w;
        if (t >= nbuk) return;
        int c0 = counts[(size_t)(lane * 2) * nbuk + t];
        int c1 = counts[(size_t)(lane * 2 + 1) * nbuk + t];
        int s = c0 + c1;
        int x = s;
#pragma unroll
        for (int d = 1; d < 64; d <<= 1) {
            int y = __shfl_up(x, (unsigned)d, 64);
            if (lane >= d) x += y;
        }
        int excl = x - s;
        counts[(size_t)(lane * 2) * nbuk + t] = excl;
        counts[(size_t)(lane * 2 + 1) * nbuk + t] = excl + c0;
        if (lane == 63) tot[t] = x;
    } else {
        int i = (b - nscan) * 256 + threadIdx.x;
        if (i >= n) return;
        int r = i >> RBITS;
        int w = (i & (RSIZE - 1)) >> 1, sh = (i & 1) << 4;
        unsigned int s = 0;
        for (int bi = 0; bi < NB2; ++bi)
            s += (gcounts[(size_t)(r * NB2 + bi) * HWORDS + w] >> sh) & 0xffffu;
        dinv[i] = rsqrtf((float)max((int)s, 1));
    }
}

// ---- K_C: scatter with inline bstart prefix (block 0 publishes bstart) -----
__global__ __launch_bounds__(256) void scatter_kernel(
    const int* __restrict__ row, const int* __restrict__ col,
    const int* __restrict__ bases, const int* __restrict__ tot,
    unsigned int* __restrict__ tmp, int* __restrict__ bstart,
    int E, int nbuk, int bshift)
{
    __shared__ int scanbuf[256];
    __shared__ int bst[1024];
    __shared__ int cur[1024];
    int t = threadIdx.x;
    int v[4];
    int s = 0;
#pragma unroll
    for (int k = 0; k < 4; ++k) {
        int idx = t * 4 + k;
        v[k] = (idx < nbuk) ? tot[idx] : 0;
        s += v[k];
    }
    scanbuf[t] = s;
    __syncthreads();
    for (int d = 1; d < 256; d <<= 1) {
        int y = (t >= d) ? scanbuf[t - d] : 0;
        __syncthreads();
        scanbuf[t] += y;
        __syncthreads();
    }
    int run = scanbuf[t] - s;
#pragma unroll
    for (int k = 0; k < 4; ++k) {
        int idx = t * 4 + k;
        if (idx < nbuk) bst[idx] = run;
        run += v[k];
    }
    __syncthreads();
    const int* mybase = bases + (size_t)blockIdx.x * nbuk;
    for (int i = t; i < nbuk; i += 256) cur[i] = bst[i] + mybase[i];
    if (blockIdx.x == 0) {
        for (int i = t; i < nbuk; i += 256) bstart[i] = bst[i];
        if (t == 0) bstart[nbuk] = E;
    }
    __syncthreads();
    int chunk = (E + NB1 - 1) / NB1;
    int e0 = blockIdx.x * chunk, e1 = min(E, e0 + chunk);
    int rsh = 32 - bshift;
    unsigned int smask = (1u << bshift) - 1u;
    for (int e = e0 + t; e < e1; e += 256) {
        int c = col[e];
        int pos = atomicAdd(&cur[c >> bshift], 1);
        tmp[pos] = (((unsigned int)c & smask) << rsh) | (unsigned int)row[e];
    }
}

// ---- K_D: group each bucket by exact col; emit off[] and csr_row[] ---------
__global__ __launch_bounds__(256) void bucket_group_kernel(
    const unsigned int* __restrict__ tmp, const int* __restrict__ bstart,
    int* __restrict__ off, int* __restrict__ csr, int n, int E, int bshift)
{
    __shared__ int subh[4096];
    const int b = blockIdx.x;
    const int tid = threadIdx.x;
    const int subb = 1 << bshift;
    const int rsh = 32 - bshift;
    const unsigned int rmask = (1u << rsh) - 1u;
    int beg = bstart[b], end = bstart[b + 1];

    for (int i = tid; i < subb; i += 256) subh[i] = 0;
    __syncthreads();
    for (int i = beg + tid; i < end; i += 256)
        atomicAdd(&subh[tmp[i] >> rsh], 1);
    __syncthreads();
    if (subb <= 64) {
        if (tid < 64) {
            int v = (tid < subb) ? subh[tid] : 0;
            int x = v;
            for (int d = 1; d < 64; d <<= 1) {
                int y = __shfl_up(x, (unsigned)d, 64);
                if (tid >= d) x += y;
            }
            if (tid < subb) subh[tid] = x - v;
        }
    } else {
        if (tid == 0) {
            int run = 0;
            for (int i = 0; i < subb; ++i) { int c = subh[i]; subh[i] = run; run += c; }
        }
    }
    __syncthreads();
    int c0 = b << bshift;
    for (int i = tid; i < subb; i += 256) {
        int c = c0 + i;
        if (c < n) off[c] = beg + subh[i];
    }
    if (b == (int)gridDim.x - 1 && tid == 0) off[n] = E;
    __syncthreads();
    for (int i = beg + tid; i < end; i += 256) {
        unsigned int v = tmp[i];
        int rank = atomicAdd(&subh[v >> rsh], 1);
        csr[beg + rank] = (int)(v & rmask);
    }
}

// ---------------- transform: bf16 MFMA GEMM --------------------------------
// W pre-converted/pre-swizzled (wbuf); H swizzled-staged (convert for fp32 in,
// linear int4 copy for pre-swizzled bf16 in).
template <bool BF16IN>
__global__ __launch_bounds__(256) void transform_kernel(
    const void* __restrict__ hin_v, const unsigned short* __restrict__ wbuf,
    const float* __restrict__ bt, const float* __restrict__ Wg,
    const float* __restrict__ bg, const float* __restrict__ dinv,
    unsigned short* __restrict__ h1b, float* __restrict__ aout, int n)
{
    __shared__ __align__(16) unsigned short h_s[BM * DIM];   // 32 KB
    __shared__ __align__(16) unsigned short w_s[DIM * DIM];  // 32 KB
    __shared__ float p_s[BM];

    const int tid = threadIdx.x;
    const int node0 = blockIdx.x * BM;
    const int lane = tid & 63;
    const int wv = tid >> 6;

    // stage W: linear int4 copy of pre-swizzled bf16 (2048 chunks)
#pragma unroll
    for (int it = 0; it < 8; ++it) {
        int g = it * 256 + tid;
        ((int4*)w_s)[g] = ((const int4*)wbuf)[g];
    }
    // stage H
    if constexpr (BF16IN) {
        const int4* hin = (const int4*)hin_v;   // pre-swizzled bf16 rows
#pragma unroll
        for (int it = 0; it < 8; ++it) {
            int g = it * 256 + tid;             // 16B chunk index
            int r = g >> 4;
            int src = node0 + r;
            if (src >= n) src = n - 1;
            ((int4*)h_s)[g] = hin[(size_t)src * 16 + (g & 15)];
        }
    } else {
        const float* hin = (const float*)hin_v;
#pragma unroll
        for (int it = 0; it < 16; ++it) {
            int g = it * 256 + tid;             // 4096 float4 slots
            int r = g >> 5;
            int c4 = g & 31;
            int src = node0 + r;
            if (src >= n) src = n - 1;
            float4 hv = *(const float4*)(hin + (size_t)src * DIM + c4 * 4);
            int chunk = (c4 >> 1) ^ (r & 15);
            int base = r * DIM + chunk * 8 + (c4 & 1) * 4;
            h_s[base + 0] = f2b(hv.x); h_s[base + 1] = f2b(hv.y);
            h_s[base + 2] = f2b(hv.z); h_s[base + 3] = f2b(hv.w);
        }
    }
    __syncthreads();

    f32x16 acc[4] = {};
    const int l31 = lane & 31;
    const int asel = lane >> 5;
    const int swz = l31 & 15;
    const unsigned short* ha = h_s + (wv * 32 + l31) * DIM;
#pragma unroll
    for (int ks = 0; ks < 8; ++ks) {
        int ch = ((ks * 2 + asel) ^ swz) * 8;
        bf16x8 av = *(const bf16x8*)(ha + ch);
#pragma unroll
        for (int cf = 0; cf < 4; ++cf) {
            bf16x8 bv = *(const bf16x8*)(w_s + (cf * 32 + l31) * DIM + ch);
            acc[cf] = __builtin_amdgcn_mfma_f32_32x32x16_bf16(av, bv, acc[cf], 0, 0, 0);
        }
    }
    __syncthreads();

    float btc[4], wgc[4];
#pragma unroll
    for (int cf = 0; cf < 4; ++cf) {
        btc[cf] = bt[cf * 32 + l31];
        wgc[cf] = Wg[cf * 32 + l31];
    }
    float p[16];
#pragma unroll
    for (int q = 0; q < 16; ++q) p[q] = 0.0f;
#pragma unroll
    for (int cf = 0; cf < 4; ++cf) {
#pragma unroll
        for (int q = 0; q < 16; ++q) {
            float v = acc[cf][q] + btc[cf];
            p[q] = fmaf(v, wgc[cf], p[q]);
            int row = (q & 3) + 8 * (q >> 2) + 4 * asel;
            h_s[(wv * 32 + row) * DIM + cf * 32 + l31] = f2b(v);
        }
    }
#pragma unroll
    for (int m = 1; m < 32; m <<= 1) {
#pragma unroll
        for (int q = 0; q < 16; ++q) p[q] += __shfl_xor(p[q], m, 64);
    }
    if (l31 == 0) {
#pragma unroll
        for (int q = 0; q < 16; ++q) {
            int row = (q & 3) + 8 * (q >> 2) + 4 * asel;
            p_s[wv * 32 + row] = p[q];
        }
    }
    __syncthreads();

#pragma unroll
    for (int it = 0; it < 8; ++it) {
        int g = it * 256 + tid;
        int r = g >> 4;
        int c = g & 15;
        int4 v = *(const int4*)(h_s + r * DIM + c * 8);
        int dst = node0 + r;
        if (dst < n) *(int4*)(h1b + (size_t)dst * DIM + c * 8) = v;
    }

    if (tid < BM) {
        int node = node0 + tid;
        if (node < n) aout[node] = tanhf(p_s[tid] + bg[0]) * dinv[node];
    }
}

// ---------------- aggregation: out[c] = relu(dinv[c]*sum(a[r]*h1[r]) + h1[c])
// BF16OUT writes hbuf in the transform's swizzled chunk order; nt stores keep
// the h1b gather set cached.
template <bool BF16OUT>
__global__ __launch_bounds__(256) void agg_kernel(
    const int* __restrict__ off, const int* __restrict__ csr_row,
    const float* __restrict__ a, const float* __restrict__ dinv,
    const unsigned short* __restrict__ h1b, void* __restrict__ out_v, int n)
{
    int node = blockIdx.x * 4 + (threadIdx.x >> 6);
    if (node >= n) return;
    int lane = threadIdx.x & 63;
    int beg = off[node], end = off[node + 1];
    const unsigned int* hb = (const unsigned int*)h1b;
    float s0x = 0.f, s0y = 0.f, s1x = 0.f, s1y = 0.f;
    float s2x = 0.f, s2y = 0.f, s3x = 0.f, s3y = 0.f;
    int s = beg;
    for (; s + 4 <= end; s += 4) {
        int r0 = csr_row[s], r1 = csr_row[s + 1], r2 = csr_row[s + 2], r3 = csr_row[s + 3];
        float a0 = a[r0], a1 = a[r1], a2 = a[r2], a3 = a[r3];
        unsigned int u0 = hb[(size_t)r0 * 64 + lane];
        unsigned int u1 = hb[(size_t)r1 * 64 + lane];
        unsigned int u2 = hb[(size_t)r2 * 64 + lane];
        unsigned int u3 = hb[(size_t)r3 * 64 + lane];
        s0x = fmaf(a0, blo(u0), s0x); s0y = fmaf(a0, bhi(u0), s0y);
        s1x = fmaf(a1, blo(u1), s1x); s1y = fmaf(a1, bhi(u1), s1y);
        s2x = fmaf(a2, blo(u2), s2x); s2y = fmaf(a2, bhi(u2), s2y);
        s3x = fmaf(a3, blo(u3), s3x); s3y = fmaf(a3, bhi(u3), s3y);
    }
    for (; s < end; ++s) {
        int r0 = csr_row[s];
        float a0 = a[r0];
        unsigned int u0 = hb[(size_t)r0 * 64 + lane];
        s0x = fmaf(a0, blo(u0), s0x); s0y = fmaf(a0, bhi(u0), s0y);
    }
    float dv = dinv[node];
    unsigned int ur = hb[(size_t)node * 64 + lane];
    float ox = fmaxf(fmaf(dv, s0x + s1x + s2x + s3x, blo(ur)), 0.0f);
    float oy = fmaxf(fmaf(dv, s0y + s1y + s2y + s3y, bhi(ur)), 0.0f);
    if constexpr (BF16OUT) {
        unsigned int pk = (unsigned int)f2b(ox) | ((unsigned int)f2b(oy) << 16);
        int pos = (((lane >> 2) ^ (node & 15)) << 2) + (lane & 3);
        __builtin_nontemporal_store(pk, (unsigned int*)out_v + (size_t)node * 64 + pos);
    } else {
        float* fp = (float*)out_v + ((size_t)node * 64 + lane) * 2;
        __builtin_nontemporal_store(ox, fp);
        __builtin_nontemporal_store(oy, fp + 1);
    }
}

extern "C" void kernel_launch(void* const* d_in, const int* in_sizes, int n_in,
                              void* d_out, int out_size, void* d_ws, size_t ws_size,
                              hipStream_t stream) {
    const float* x    = (const float*)d_in[0];
    const int*   edge = (const int*)d_in[1];
    const float* Wt   = (const float*)d_in[2];
    const float* bt   = (const float*)d_in[3];
    const float* Wg   = (const float*)d_in[4];
    const float* bg   = (const float*)d_in[5];
    float* out = (float*)d_out;

    const int n = in_sizes[0] / DIM;      // 50000
    const int E = in_sizes[1] / 2;        // 600000
    const int* row = edge;
    const int* col = edge + E;

    int bshift = 6;
    while (((n + (1 << bshift) - 1) >> bshift) > 1024) ++bshift;
    const int nbuk = (n + (1 << bshift) - 1) >> bshift;
    const int nr = (n + RSIZE - 1) >> RBITS;   // = 2
    const int ndeg = nr * NB2;                  // = 64

    // ---- byte-carved workspace ----
    char* base = (char*)d_ws;
    size_t o = 0;
    auto carve = [&](size_t bytes) -> void* {
        void* p = base + o;
        o += (bytes + 255) & ~(size_t)255;
        return p;
    };
    unsigned short* h1b  = (unsigned short*)carve((size_t)n * DIM * 2);
    unsigned short* hbuf = (unsigned short*)carve((size_t)n * DIM * 2);
    unsigned short* wbuf = (unsigned short*)carve((size_t)2 * DIM * DIM * 2);
    float* dinv          = (float*)carve((size_t)n * 4);
    float* a             = (float*)carve((size_t)n * 4);
    int*   off           = (int*)carve((size_t)(n + 1) * 4);
    int*   csr           = (int*)carve((size_t)E * 4);
    unsigned int* tmp    = (unsigned int*)carve((size_t)E * 4);
    int*   counts        = (int*)carve((size_t)NB1 * nbuk * 4);
    int*   bstart        = (int*)carve((size_t)(nbuk + 1) * 4);
    int*   tot           = (int*)carve((size_t)nbuk * 4);
    unsigned int* gcounts = (unsigned int*)carve((size_t)ndeg * HWORDS * 4);

    // ---- preprocessing: 4 kernels, no global atomics ----
    hists_kernel<<<ndeg + NB1 + NWC, 256, 0, stream>>>(
        row, col, Wt, wbuf, gcounts, counts, E, ndeg, nbuk, bshift);
    const int nscan = (nbuk + 3) / 4;
    const int ndinv = (n + 255) / 256;
    scan_dinv_kernel<<<nscan + ndinv, 256, 0, stream>>>(counts, tot, gcounts, dinv,
                                                        nbuk, n, nscan);
    scatter_kernel<<<NB1, 256, 0, stream>>>(row, col, counts, tot, tmp, bstart,
                                            E, nbuk, bshift);
    bucket_group_kernel<<<nbuk, 256, 0, stream>>>(tmp, bstart, off, csr, n, E, bshift);

    // ---- two FA layers (swizzled bf16 inter-layer handoff) ----
    const int gt = (n + BM - 1) / BM;
    const int ga = (n + 3) / 4;

    transform_kernel<false><<<gt, 256, 0, stream>>>(
        x, wbuf, bt, Wg, bg, dinv, h1b, a, n);
    agg_kernel<true><<<ga, 256, 0, stream>>>(off, csr, a, dinv, h1b, hbuf, n);

    transform_kernel<true><<<gt, 256, 0, stream>>>(
        hbuf, wbuf + DIM * DIM, bt + DIM, Wg + DIM, bg + 1, dinv, h1b, a, n);
    agg_kernel<false><<<ga, 256, 0, stream>>>(off, csr, a, dinv, h1b, out, n);
}